// Round 4
// baseline (126.626 us; speedup 1.0000x reference)
//
#include <hip/hip_runtime.h>
#include <hip/hip_bf16.h>

#define B_ 4
#define C_IN 128
#define C_OUT 256
#define N_IN 40962
#define N_OUT 10242
#define EPS_ 1e-5f

typedef __attribute__((ext_vector_type(8))) short bf16x8;
typedef __attribute__((ext_vector_type(4))) float f32x4;

__device__ __forceinline__ float bf2f(unsigned short u) {
    union { unsigned int i; float f; } c;
    c.i = ((unsigned int)u) << 16;
    return c.f;
}
__device__ __forceinline__ unsigned short f2bf(float f) {
    union { float f; unsigned int i; } c;
    c.f = f;
    unsigned int r = c.i + 0x7FFFu + ((c.i >> 16) & 1u);  // RNE
    return (unsigned short)(r >> 16);
}

// ---------------------------------------------------------------------------
// K1: transpose x[b][k][i] (f32) -> xT[b][i][k] (bf16)
// ---------------------------------------------------------------------------
#define IBLK 64
#define NB_I ((N_IN + IBLK - 1) / IBLK)  // 641

__global__ __launch_bounds__(256) void k_transpose(const float* __restrict__ x,
                                                   unsigned short* __restrict__ xT) {
    __shared__ float tile[IBLK][C_IN + 1];
    int b  = blockIdx.x / NB_I;
    int ib = blockIdx.x % NB_I;
    int i0 = ib * IBLK;
    int t = threadIdx.x;
    int lane = t & 63;
    int q = t >> 6;

    const float* xb = x + (size_t)b * C_IN * N_IN;
    int i = i0 + lane;
    if (i < N_IN) {
#pragma unroll
        for (int p = 0; p < 32; p++) {
            int k = p * 4 + q;
            tile[lane][k] = xb[(size_t)k * N_IN + i];
        }
    }
    __syncthreads();

    unsigned short* xTb = xT + (size_t)b * N_IN * C_IN;
#pragma unroll
    for (int p = 0; p < 16; p++) {
        int il = p * 4 + q;
        int gi = i0 + il;
        if (gi < N_IN) {
            int k2 = lane * 2;
            float a = tile[il][k2];
            float c = tile[il][k2 + 1];
            unsigned int pk = (unsigned int)f2bf(a) | ((unsigned int)f2bf(c) << 16);
            *reinterpret_cast<unsigned int*>(xTb + (size_t)gi * C_IN + k2) = pk;
        }
    }
}

// ---------------------------------------------------------------------------
// K2: fused gather-mean + stats GEMM.
//   Phase 1: gather 32 g-rows into LDS (padded) + write g to global (bf16).
//   Phase 2: MFMA GEMM from LDS, bias, per-channel partials -> psum[bid].
// ---------------------------------------------------------------------------
#define GT 32
#define NB_GS ((N_OUT + GT - 1) / GT)   // 321
#define NBLK_GS (B_ * NB_GS)            // 1284
#define LROW (C_IN + 8)                 // 136 shorts: row stride 272B

__global__ __launch_bounds__(256) void k_gstats(const unsigned short* __restrict__ xT,
                                                const int* __restrict__ idx,
                                                const float* __restrict__ W,
                                                const float* __restrict__ bias,
                                                unsigned short* __restrict__ g,
                                                float* __restrict__ psum) {
    __shared__ unsigned short gl[GT][LROW];
    __shared__ float red[2][C_OUT];
    int bid = blockIdx.x;
    int b  = bid / NB_GS;
    int nb = bid % NB_GS;
    int n0 = nb * GT;
    int t = threadIdx.x;
    int grp = t >> 4, c = t & 15;

    const unsigned short* xTb = xT + (size_t)b * N_IN * C_IN;
    unsigned short* gb = g + (size_t)b * N_OUT * C_IN;

    // Phase 1: gather-mean (2 reps of 16 rows)
#pragma unroll
    for (int rep = 0; rep < 2; rep++) {
        int nrow = rep * 16 + grp;
        int n = n0 + nrow;
        int nc = (n < N_OUT) ? n : (N_OUT - 1);
        const int* ip = idx + 7 * nc;
        float s[8];
#pragma unroll
        for (int e = 0; e < 8; e++) s[e] = 0.f;
#pragma unroll
        for (int j = 0; j < 7; j++) {
            int id = ip[j];
            bf16x8 v = *reinterpret_cast<const bf16x8*>(xTb + (size_t)id * C_IN + c * 8);
#pragma unroll
            for (int e = 0; e < 8; e++) s[e] += bf2f((unsigned short)v[e]);
        }
        const float inv7 = 1.0f / 7.0f;
        bf16x8 r;
#pragma unroll
        for (int e = 0; e < 8; e++) r[e] = (short)f2bf(s[e] * inv7);
        *reinterpret_cast<bf16x8*>(&gl[nrow][c * 8]) = r;
        if (n < N_OUT)
            *reinterpret_cast<bf16x8*>(gb + (size_t)n * C_IN + c * 8) = r;
    }
    __syncthreads();

    // Phase 2: GEMM. Wave w owns channels [w*64, w*64+64) x 32 n.
    int w = t >> 6, l = t & 63, lr = l & 15, lg = l >> 4;
    int wbase = w * 64;

    bf16x8 afrag[4][4];
#pragma unroll
    for (int mt = 0; mt < 4; mt++) {
        const float* wr = W + (size_t)(wbase + mt * 16 + lr) * C_IN;
#pragma unroll
        for (int ks = 0; ks < 4; ks++) {
            int k0 = ks * 32 + lg * 8;
            f32x4 w0 = *reinterpret_cast<const f32x4*>(wr + k0);
            f32x4 w1 = *reinterpret_cast<const f32x4*>(wr + k0 + 4);
            bf16x8 f;
#pragma unroll
            for (int e = 0; e < 4; e++) {
                f[e]     = (short)f2bf(w0[e]);
                f[e + 4] = (short)f2bf(w1[e]);
            }
            afrag[mt][ks] = f;
        }
    }

    f32x4 acc[4][2];
#pragma unroll
    for (int mt = 0; mt < 4; mt++)
#pragma unroll
        for (int nt = 0; nt < 2; nt++) acc[mt][nt] = (f32x4)(0.0f);

#pragma unroll
    for (int nt = 0; nt < 2; nt++) {
        bf16x8 bfr[4];
#pragma unroll
        for (int ks = 0; ks < 4; ks++)
            bfr[ks] = *reinterpret_cast<const bf16x8*>(&gl[nt * 16 + lr][ks * 32 + lg * 8]);
#pragma unroll
        for (int mt = 0; mt < 4; mt++)
#pragma unroll
            for (int ks = 0; ks < 4; ks++)
                acc[mt][nt] = __builtin_amdgcn_mfma_f32_16x16x32_bf16(afrag[mt][ks], bfr[ks],
                                                                     acc[mt][nt], 0, 0, 0);
    }

    // Epilogue: bias + partial sums -> psum[bid]
    float ps1[16], ps2[16];
#pragma unroll
    for (int m = 0; m < 16; m++) { ps1[m] = 0.f; ps2[m] = 0.f; }
#pragma unroll
    for (int mt = 0; mt < 4; mt++) {
#pragma unroll
        for (int j = 0; j < 4; j++) {
            int o = wbase + mt * 16 + lg * 4 + j;
            float bv = bias[o];
#pragma unroll
            for (int nt = 0; nt < 2; nt++) {
                int n = n0 + nt * 16 + lr;
                if (n < N_OUT) {
                    float v = acc[mt][nt][j] + bv;
                    ps1[mt * 4 + j] += v;
                    ps2[mt * 4 + j] += v * v;
                }
            }
        }
    }
#pragma unroll
    for (int m = 0; m < 16; m++) {
        float a = ps1[m], cc = ps2[m];
#pragma unroll
        for (int d = 1; d < 16; d <<= 1) {
            a  += __shfl_xor(a, d, 64);
            cc += __shfl_xor(cc, d, 64);
        }
        if (lr == 0) {
            int mt = m >> 2, j = m & 3;
            int o = wbase + mt * 16 + lg * 4 + j;
            red[0][o] = a;
            red[1][o] = cc;
        }
    }
    __syncthreads();
    float* pb = psum + (size_t)bid * 2 * C_OUT;
    pb[t] = red[0][t];
    pb[C_OUT + t] = red[1][t];
}

// ---------------------------------------------------------------------------
// K3a: tree reduce psum[1284][512] -> psum2[32][512]
// ---------------------------------------------------------------------------
#define RED_BLKS 32
__global__ __launch_bounds__(256) void k_reduce(const float* __restrict__ psum,
                                                float* __restrict__ psum2) {
    int r = blockIdx.x;
    int t = threadIdx.x;
    float a = 0.f, c = 0.f;
    for (int i = r; i < NBLK_GS; i += RED_BLKS) {
        const float* pb = psum + (size_t)i * 2 * C_OUT;
        a += pb[t];
        c += pb[C_OUT + t];
    }
    float* qb = psum2 + (size_t)r * 2 * C_OUT;
    qb[t] = a;
    qb[C_OUT + t] = c;
}

// K3b: finalize -> scale/shift (bias folded in)
__global__ void k_finalize(const float* __restrict__ psum2, const float* __restrict__ bias,
                           const float* __restrict__ gamma, const float* __restrict__ beta,
                           float* __restrict__ ss) {
    int o = threadIdx.x;
    float s1 = 0.f, s2 = 0.f;
#pragma unroll 4
    for (int r = 0; r < RED_BLKS; r++) {
        s1 += psum2[(size_t)r * 2 * C_OUT + o];
        s2 += psum2[(size_t)r * 2 * C_OUT + C_OUT + o];
    }
    const float cnt = (float)(B_ * N_OUT);
    float mean = s1 / cnt;
    float var = s2 / cnt - mean * mean;
    float a = gamma[o] * rsqrtf(var + EPS_);
    ss[o] = a;
    ss[C_OUT + o] = a * bias[o] + beta[o] - a * mean;
}

// ---------------------------------------------------------------------------
// K4: GEMM again (g from global, W f32 in-register cvt) + normalize + out
// ---------------------------------------------------------------------------
#define NT2 32
#define NB_N2 ((N_OUT + NT2 - 1) / NT2)  // 321

__global__ __launch_bounds__(256) void k_final_gemm(const unsigned short* __restrict__ g,
                                                    const float* __restrict__ W,
                                                    const float* __restrict__ ss,
                                                    float* __restrict__ out) {
    int b  = blockIdx.x / NB_N2;
    int nb = blockIdx.x % NB_N2;
    int n0 = nb * NT2;
    int t = threadIdx.x;
    int w = t >> 6, l = t & 63, lr = l & 15, lg = l >> 4;
    int wbase = w * 64;

    const unsigned short* gb = g + (size_t)b * N_OUT * C_IN;
    bf16x8 bfrag[2][4];
#pragma unroll
    for (int nt = 0; nt < 2; nt++) {
        int n = n0 + nt * 16 + lr;
        const unsigned short* gr = gb + (size_t)((n < N_OUT) ? n : 0) * C_IN;
#pragma unroll
        for (int ks = 0; ks < 4; ks++)
            bfrag[nt][ks] = *reinterpret_cast<const bf16x8*>(gr + ks * 32 + lg * 8);
    }

    f32x4 acc[4][2];
#pragma unroll
    for (int mt = 0; mt < 4; mt++)
#pragma unroll
        for (int nt = 0; nt < 2; nt++) acc[mt][nt] = (f32x4)(0.0f);

#pragma unroll
    for (int mt = 0; mt < 4; mt++) {
        const float* wr = W + (size_t)(wbase + mt * 16 + lr) * C_IN;
        bf16x8 af[4];
#pragma unroll
        for (int ks = 0; ks < 4; ks++) {
            int k0 = ks * 32 + lg * 8;
            f32x4 w0 = *reinterpret_cast<const f32x4*>(wr + k0);
            f32x4 w1 = *reinterpret_cast<const f32x4*>(wr + k0 + 4);
            bf16x8 f;
#pragma unroll
            for (int e = 0; e < 4; e++) {
                f[e]     = (short)f2bf(w0[e]);
                f[e + 4] = (short)f2bf(w1[e]);
            }
            af[ks] = f;
        }
#pragma unroll
        for (int nt = 0; nt < 2; nt++)
#pragma unroll
            for (int ks = 0; ks < 4; ks++)
                acc[mt][nt] = __builtin_amdgcn_mfma_f32_16x16x32_bf16(af[ks], bfrag[nt][ks],
                                                                     acc[mt][nt], 0, 0, 0);
    }

    float* ob = out + (size_t)b * C_OUT * N_OUT;
#pragma unroll
    for (int mt = 0; mt < 4; mt++) {
#pragma unroll
        for (int j = 0; j < 4; j++) {
            int o = wbase + mt * 16 + lg * 4 + j;
            float a = ss[o];
            float sh = ss[C_OUT + o];
#pragma unroll
            for (int nt = 0; nt < 2; nt++) {
                int n = n0 + nt * 16 + lr;
                if (n < N_OUT) ob[(size_t)o * N_OUT + n] = a * acc[mt][nt][j] + sh;
            }
        }
    }
}

// ---------------------------------------------------------------------------
extern "C" void kernel_launch(void* const* d_in, const int* in_sizes, int n_in,
                              void* d_out, int out_size, void* d_ws, size_t ws_size,
                              hipStream_t stream) {
    const float* x     = (const float*)d_in[0];
    const int*   idx   = (const int*)d_in[1];
    const float* W     = (const float*)d_in[2];
    const float* bias  = (const float*)d_in[3];
    const float* gamma = (const float*)d_in[4];
    const float* beta  = (const float*)d_in[5];
    float* out = (float*)d_out;

    const size_t xt_bytes = (size_t)B_ * N_IN * C_IN * sizeof(unsigned short);   // 41,945,088
    const size_t g_bytes  = (size_t)B_ * N_OUT * C_IN * sizeof(unsigned short);  // 10,487,808
    unsigned short* xT = (unsigned short*)d_ws;
    unsigned short* gg = (unsigned short*)((char*)d_ws + xt_bytes);
    float* psum  = (float*)((char*)d_ws + xt_bytes + g_bytes);                // 2.63 MB
    float* psum2 = psum + (size_t)NBLK_GS * 2 * C_OUT;
    float* ss    = psum2 + (size_t)RED_BLKS * 2 * C_OUT;

    k_transpose<<<B_ * NB_I, 256, 0, stream>>>(x, xT);
    k_gstats<<<NBLK_GS, 256, 0, stream>>>(xT, idx, W, bias, gg, psum);
    k_reduce<<<RED_BLKS, 256, 0, stream>>>(psum, psum2);
    k_finalize<<<1, C_OUT, 0, stream>>>(psum2, bias, gamma, beta, ss);
    k_final_gemm<<<B_ * NB_N2, 256, 0, stream>>>(gg, W, ss, out);
}

// Round 5
// 93.497 us; speedup vs baseline: 1.3543x; 1.3543x over previous
//
#include <hip/hip_runtime.h>
#include <hip/hip_bf16.h>

#define B_ 4
#define C_IN 128
#define C_OUT 256
#define N_IN 40962
#define N_OUT 10242
#define EPS_ 1e-5f

typedef __attribute__((ext_vector_type(8))) short bf16x8;
typedef __attribute__((ext_vector_type(4))) float f32x4;

__device__ __forceinline__ float bf2f(unsigned short u) {
    union { unsigned int i; float f; } c;
    c.i = ((unsigned int)u) << 16;
    return c.f;
}
__device__ __forceinline__ unsigned short f2bf(float f) {
    union { float f; unsigned int i; } c;
    c.f = f;
    unsigned int r = c.i + 0x7FFFu + ((c.i >> 16) & 1u);  // RNE
    return (unsigned short)(r >> 16);
}

// ---------------------------------------------------------------------------
// K1: transpose x[b][k][i] (f32) -> xT[b][i][k] (bf16); trailing blocks do
//     the W f32->bf16 conversion (saves a separate launch).
// ---------------------------------------------------------------------------
#define IBLK 64
#define NB_I ((N_IN + IBLK - 1) / IBLK)   // 641
#define WCONV_BLKS ((C_OUT * C_IN) / 256) // 128

__global__ __launch_bounds__(256) void k_transpose(const float* __restrict__ x,
                                                   unsigned short* __restrict__ xT,
                                                   const float* __restrict__ W,
                                                   unsigned short* __restrict__ Wb) {
    if (blockIdx.x >= B_ * NB_I) {
        int i = (blockIdx.x - B_ * NB_I) * 256 + threadIdx.x;
        Wb[i] = f2bf(W[i]);
        return;
    }
    __shared__ float tile[IBLK][C_IN + 1];
    int b  = blockIdx.x / NB_I;
    int ib = blockIdx.x % NB_I;
    int i0 = ib * IBLK;
    int t = threadIdx.x;
    int lane = t & 63;
    int q = t >> 6;

    const float* xb = x + (size_t)b * C_IN * N_IN;
    int i = i0 + lane;
    if (i < N_IN) {
#pragma unroll
        for (int p = 0; p < 32; p++) {
            int k = p * 4 + q;
            tile[lane][k] = xb[(size_t)k * N_IN + i];
        }
    }
    __syncthreads();

    unsigned short* xTb = xT + (size_t)b * N_IN * C_IN;
#pragma unroll
    for (int p = 0; p < 16; p++) {
        int il = p * 4 + q;
        int gi = i0 + il;
        if (gi < N_IN) {
            int k2 = lane * 2;
            float a = tile[il][k2];
            float c = tile[il][k2 + 1];
            unsigned int pk = (unsigned int)f2bf(a) | ((unsigned int)f2bf(c) << 16);
            *reinterpret_cast<unsigned int*>(xTb + (size_t)gi * C_IN + k2) = pk;
        }
    }
}

// ---------------------------------------------------------------------------
// K2: gather-mean: g[b][n][k] = mean_j xT[b][idx[7n+j]][k]  (bf16 out)
// 16 threads per n; max TLP (2564 blocks) for the random L3 reads.
// ---------------------------------------------------------------------------
#define GNB 16
#define NB_G ((N_OUT + GNB - 1) / GNB)  // 641

__global__ __launch_bounds__(256) void k_gather(const unsigned short* __restrict__ xT,
                                                const int* __restrict__ idx,
                                                unsigned short* __restrict__ g) {
    int b  = blockIdx.x / NB_G;
    int nb = blockIdx.x % NB_G;
    int t = threadIdx.x;
    int n = nb * GNB + (t >> 4);
    int c = t & 15;
    if (n >= N_OUT) return;

    const unsigned short* xTb = xT + (size_t)b * N_IN * C_IN;
    const int* ip = idx + 7 * n;
    float s[8];
#pragma unroll
    for (int e = 0; e < 8; e++) s[e] = 0.f;
#pragma unroll
    for (int j = 0; j < 7; j++) {
        int id = ip[j];
        bf16x8 v = *reinterpret_cast<const bf16x8*>(xTb + (size_t)id * C_IN + c * 8);
#pragma unroll
        for (int e = 0; e < 8; e++) s[e] += bf2f((unsigned short)v[e]);
    }
    const float inv7 = 1.0f / 7.0f;
    bf16x8 r;
#pragma unroll
    for (int e = 0; e < 8; e++) r[e] = (short)f2bf(s[e] * inv7);
    *reinterpret_cast<bf16x8*>(g + ((size_t)b * N_OUT + n) * C_IN + c * 8) = r;
}

// ---------------------------------------------------------------------------
// GEMM tiling: 64-n tile per block, wave w owns 64 channels.
// ---------------------------------------------------------------------------
#define NT2 64
#define NB_N2 ((N_OUT + NT2 - 1) / NT2)  // 161
#define NBLK_GS (B_ * NB_N2)             // 644

// K3: GEMM -> per-block per-channel partials (no atomics)
__global__ __launch_bounds__(256, 2) void k_stats_gemm(const unsigned short* __restrict__ g,
                                                       const unsigned short* __restrict__ Wb,
                                                       const float* __restrict__ bias,
                                                       float* __restrict__ psum) {
    int bid = blockIdx.x;
    int b  = bid / NB_N2;
    int nb = bid % NB_N2;
    int n0 = nb * NT2;
    int t = threadIdx.x;
    int w = t >> 6, l = t & 63, lr = l & 15, lg = l >> 4;
    int wbase = w * 64;

    bf16x8 afrag[4][4];
#pragma unroll
    for (int mt = 0; mt < 4; mt++)
#pragma unroll
        for (int ks = 0; ks < 4; ks++)
            afrag[mt][ks] = *reinterpret_cast<const bf16x8*>(
                Wb + (size_t)(wbase + mt * 16 + lr) * C_IN + ks * 32 + lg * 8);

    f32x4 acc[4][4];
#pragma unroll
    for (int mt = 0; mt < 4; mt++)
#pragma unroll
        for (int nt = 0; nt < 4; nt++) acc[mt][nt] = (f32x4)(0.0f);

    const unsigned short* gb = g + (size_t)b * N_OUT * C_IN;
#pragma unroll
    for (int nt = 0; nt < 4; nt++) {
        int n = n0 + nt * 16 + lr;
        const unsigned short* gr = gb + (size_t)((n < N_OUT) ? n : 0) * C_IN;
#pragma unroll
        for (int ks = 0; ks < 4; ks++) {
            bf16x8 bfr = *reinterpret_cast<const bf16x8*>(gr + ks * 32 + lg * 8);
#pragma unroll
            for (int mt = 0; mt < 4; mt++)
                acc[mt][nt] = __builtin_amdgcn_mfma_f32_16x16x32_bf16(afrag[mt][ks], bfr,
                                                                     acc[mt][nt], 0, 0, 0);
        }
    }

    float ps1[16], ps2[16];
#pragma unroll
    for (int m = 0; m < 16; m++) { ps1[m] = 0.f; ps2[m] = 0.f; }
#pragma unroll
    for (int mt = 0; mt < 4; mt++) {
#pragma unroll
        for (int j = 0; j < 4; j++) {
            int o = wbase + mt * 16 + lg * 4 + j;
            float bv = bias[o];
#pragma unroll
            for (int nt = 0; nt < 4; nt++) {
                int n = n0 + nt * 16 + lr;
                if (n < N_OUT) {
                    float v = acc[mt][nt][j] + bv;
                    ps1[mt * 4 + j] += v;
                    ps2[mt * 4 + j] += v * v;
                }
            }
        }
    }

    __shared__ float red[2][C_OUT];
#pragma unroll
    for (int m = 0; m < 16; m++) {
        float a = ps1[m], cc = ps2[m];
#pragma unroll
        for (int d = 1; d < 16; d <<= 1) {
            a  += __shfl_xor(a, d, 64);
            cc += __shfl_xor(cc, d, 64);
        }
        if (lr == 0) {
            int mt = m >> 2, j = m & 3;
            int o = wbase + mt * 16 + lg * 4 + j;
            red[0][o] = a;
            red[1][o] = cc;
        }
    }
    __syncthreads();
    float* pb = psum + (size_t)bid * 2 * C_OUT;
    pb[t] = red[0][t];
    pb[C_OUT + t] = red[1][t];
}

// K4a: tree reduce psum[644][512] -> psum2[32][512]
#define RED_BLKS 32
__global__ __launch_bounds__(256) void k_reduce(const float* __restrict__ psum,
                                                float* __restrict__ psum2) {
    int r = blockIdx.x;
    int t = threadIdx.x;
    float a = 0.f, c = 0.f;
    for (int i = r; i < NBLK_GS; i += RED_BLKS) {
        const float* pb = psum + (size_t)i * 2 * C_OUT;
        a += pb[t];
        c += pb[C_OUT + t];
    }
    float* qb = psum2 + (size_t)r * 2 * C_OUT;
    qb[t] = a;
    qb[C_OUT + t] = c;
}

// K4b: finalize -> scale/shift (bias folded in)
__global__ void k_finalize(const float* __restrict__ psum2, const float* __restrict__ bias,
                           const float* __restrict__ gamma, const float* __restrict__ beta,
                           float* __restrict__ ss) {
    int o = threadIdx.x;
    float s1 = 0.f, s2 = 0.f;
#pragma unroll 4
    for (int r = 0; r < RED_BLKS; r++) {
        s1 += psum2[(size_t)r * 2 * C_OUT + o];
        s2 += psum2[(size_t)r * 2 * C_OUT + C_OUT + o];
    }
    const float cnt = (float)(B_ * N_OUT);
    float mean = s1 / cnt;
    float var = s2 / cnt - mean * mean;
    float a = gamma[o] * rsqrtf(var + EPS_);
    ss[o] = a;
    ss[C_OUT + o] = a * bias[o] + beta[o] - a * mean;
}

// ---------------------------------------------------------------------------
// K5: GEMM + normalize + write out
// ---------------------------------------------------------------------------
__global__ __launch_bounds__(256, 2) void k_final_gemm(const unsigned short* __restrict__ g,
                                                       const unsigned short* __restrict__ Wb,
                                                       const float* __restrict__ ss,
                                                       float* __restrict__ out) {
    int b  = blockIdx.x / NB_N2;
    int nb = blockIdx.x % NB_N2;
    int n0 = nb * NT2;
    int t = threadIdx.x;
    int w = t >> 6, l = t & 63, lr = l & 15, lg = l >> 4;
    int wbase = w * 64;

    bf16x8 afrag[4][4];
#pragma unroll
    for (int mt = 0; mt < 4; mt++)
#pragma unroll
        for (int ks = 0; ks < 4; ks++)
            afrag[mt][ks] = *reinterpret_cast<const bf16x8*>(
                Wb + (size_t)(wbase + mt * 16 + lr) * C_IN + ks * 32 + lg * 8);

    f32x4 acc[4][4];
#pragma unroll
    for (int mt = 0; mt < 4; mt++)
#pragma unroll
        for (int nt = 0; nt < 4; nt++) acc[mt][nt] = (f32x4)(0.0f);

    const unsigned short* gb = g + (size_t)b * N_OUT * C_IN;
#pragma unroll
    for (int nt = 0; nt < 4; nt++) {
        int n = n0 + nt * 16 + lr;
        const unsigned short* gr = gb + (size_t)((n < N_OUT) ? n : 0) * C_IN;
#pragma unroll
        for (int ks = 0; ks < 4; ks++) {
            bf16x8 bfr = *reinterpret_cast<const bf16x8*>(gr + ks * 32 + lg * 8);
#pragma unroll
            for (int mt = 0; mt < 4; mt++)
                acc[mt][nt] = __builtin_amdgcn_mfma_f32_16x16x32_bf16(afrag[mt][ks], bfr,
                                                                     acc[mt][nt], 0, 0, 0);
        }
    }

    float* ob = out + (size_t)b * C_OUT * N_OUT;
#pragma unroll
    for (int mt = 0; mt < 4; mt++) {
#pragma unroll
        for (int j = 0; j < 4; j++) {
            int o = wbase + mt * 16 + lg * 4 + j;
            float a = ss[o];
            float sh = ss[C_OUT + o];
#pragma unroll
            for (int nt = 0; nt < 4; nt++) {
                int n = n0 + nt * 16 + lr;
                if (n < N_OUT) ob[(size_t)o * N_OUT + n] = a * acc[mt][nt][j] + sh;
            }
        }
    }
}

// ---------------------------------------------------------------------------
extern "C" void kernel_launch(void* const* d_in, const int* in_sizes, int n_in,
                              void* d_out, int out_size, void* d_ws, size_t ws_size,
                              hipStream_t stream) {
    const float* x     = (const float*)d_in[0];
    const int*   idx   = (const int*)d_in[1];
    const float* W     = (const float*)d_in[2];
    const float* bias  = (const float*)d_in[3];
    const float* gamma = (const float*)d_in[4];
    const float* beta  = (const float*)d_in[5];
    float* out = (float*)d_out;

    const size_t xt_bytes = (size_t)B_ * N_IN * C_IN * sizeof(unsigned short);   // 41,945,088
    const size_t g_bytes  = (size_t)B_ * N_OUT * C_IN * sizeof(unsigned short);  // 10,487,808
    const size_t wb_bytes = (size_t)C_OUT * C_IN * sizeof(unsigned short);       // 65,536
    unsigned short* xT = (unsigned short*)d_ws;
    unsigned short* gg = (unsigned short*)((char*)d_ws + xt_bytes);
    unsigned short* Wb = (unsigned short*)((char*)d_ws + xt_bytes + g_bytes);
    float* psum  = (float*)((char*)d_ws + xt_bytes + g_bytes + wb_bytes);        // 644*512*4 = 1.32 MB
    float* psum2 = psum + (size_t)NBLK_GS * 2 * C_OUT;
    float* ss    = psum2 + (size_t)RED_BLKS * 2 * C_OUT;

    k_transpose<<<B_ * NB_I + WCONV_BLKS, 256, 0, stream>>>(x, xT, W, Wb);
    k_gather<<<B_ * NB_G, 256, 0, stream>>>(xT, idx, gg);
    k_stats_gemm<<<NBLK_GS, 256, 0, stream>>>(gg, Wb, bias, psum);
    k_reduce<<<RED_BLKS, 256, 0, stream>>>(psum, psum2);
    k_finalize<<<1, C_OUT, 0, stream>>>(psum2, bias, gamma, beta, ss);
    k_final_gemm<<<B_ * NB_N2, 256, 0, stream>>>(gg, Wb, ss, out);
}